// Round 12
// baseline (236.569 us; speedup 1.0000x reference)
//
#include <hip/hip_runtime.h>
#include <math.h>

#define DIM    2048
#define B_     64
#define HQ     16
#define HK     4
#define G_     4
#define D_     128
#define SPAST  4095
#define SEQ    4096
#define NSPLIT 4
#define KSPLIT 8
#define EPS    1e-5f

typedef short bfrag __attribute__((ext_vector_type(8)));   // 8 bf16 (4 VGPR)
typedef float facc  __attribute__((ext_vector_type(4)));   // 4 f32 acc
typedef unsigned short ushort_t;

// fp32 -> bf16, round-to-nearest-even
__device__ inline unsigned short f2bf(float f) {
    unsigned u = __float_as_uint(f);
    return (unsigned short)((u + 0x7FFFu + ((u >> 16) & 1u)) >> 16);
}

// ---------------------------------------------------------------------------
// bf16-MFMA split-K GEMM (round-8 version, measured best).
// ---------------------------------------------------------------------------
template<bool ABF16>
__global__ __launch_bounds__(256) void gemm_mfma_kernel(
    const void* __restrict__ Aptr,
    const float* __restrict__ W0, const float* __restrict__ W1,
    const float* __restrict__ W2,
    float* __restrict__ part, int N)
{
    const int K  = 2048;
    const int KS = K / KSPLIT;   // 256
    int n0 = blockIdx.x * 64;
    int ks = blockIdx.y;
    const float* W; int wc;
    if (n0 < 2048)      { W = W0; wc = n0; }
    else if (n0 < 2560) { W = W1; wc = n0 - 2048; }
    else                { W = W2; wc = n0 - 2560; }

    __shared__ bfrag a_lds[64 * 8];   // [row][chunk] 8 chunks of 8 bf16
    __shared__ bfrag w_lds[64 * 8];

    int t = threadIdx.x;
    int w = t >> 6, l = t & 63;
    int row_s = t >> 2;          // staging row 0..63 (4 threads per row)
    int q_s   = t & 3;           // staging quad: 16 elements at q_s*16
    int sw_s  = row_s & 7;
    int c0    = q_s * 2;

    facc acc[4] = {};

    const float*    Af = (const float*)Aptr;
    const ushort_t* Ab = (const ushort_t*)Aptr;
    size_t a_off = (size_t)row_s * K + (size_t)ks * KS + q_s * 16;
    const float* Wbase = W + (size_t)(wc + row_s) * K + (size_t)ks * KS + q_s * 16;

    for (int kt = 0; kt < KS; kt += 64) {
        __syncthreads();
        // ---- stage A tile ----
        if constexpr (ABF16) {
            const ushort_t* p = Ab + a_off + kt;
            bfrag v0 = *(const bfrag*)(p);
            bfrag v1 = *(const bfrag*)(p + 8);
            a_lds[row_s * 8 + ((c0    ) ^ sw_s)] = v0;
            a_lds[row_s * 8 + ((c0 + 1) ^ sw_s)] = v1;
        } else {
            const float* p = Af + a_off + kt;
            float4 f0 = *(const float4*)(p);
            float4 f1 = *(const float4*)(p + 4);
            float4 f2 = *(const float4*)(p + 8);
            float4 f3 = *(const float4*)(p + 12);
            bfrag v0, v1;
            v0[0]=f2bf(f0.x); v0[1]=f2bf(f0.y); v0[2]=f2bf(f0.z); v0[3]=f2bf(f0.w);
            v0[4]=f2bf(f1.x); v0[5]=f2bf(f1.y); v0[6]=f2bf(f1.z); v0[7]=f2bf(f1.w);
            v1[0]=f2bf(f2.x); v1[1]=f2bf(f2.y); v1[2]=f2bf(f2.z); v1[3]=f2bf(f2.w);
            v1[4]=f2bf(f3.x); v1[5]=f2bf(f3.y); v1[6]=f2bf(f3.z); v1[7]=f2bf(f3.w);
            a_lds[row_s * 8 + ((c0    ) ^ sw_s)] = v0;
            a_lds[row_s * 8 + ((c0 + 1) ^ sw_s)] = v1;
        }
        // ---- stage W tile (fp32 -> bf16) ----
        {
            const float* p = Wbase + kt;
            float4 f0 = *(const float4*)(p);
            float4 f1 = *(const float4*)(p + 4);
            float4 f2 = *(const float4*)(p + 8);
            float4 f3 = *(const float4*)(p + 12);
            bfrag v0, v1;
            v0[0]=f2bf(f0.x); v0[1]=f2bf(f0.y); v0[2]=f2bf(f0.z); v0[3]=f2bf(f0.w);
            v0[4]=f2bf(f1.x); v0[5]=f2bf(f1.y); v0[6]=f2bf(f1.z); v0[7]=f2bf(f1.w);
            v1[0]=f2bf(f2.x); v1[1]=f2bf(f2.y); v1[2]=f2bf(f2.z); v1[3]=f2bf(f2.w);
            v1[4]=f2bf(f3.x); v1[5]=f2bf(f3.y); v1[6]=f2bf(f3.z); v1[7]=f2bf(f3.w);
            w_lds[row_s * 8 + ((c0    ) ^ sw_s)] = v0;
            w_lds[row_s * 8 + ((c0 + 1) ^ sw_s)] = v1;
        }
        __syncthreads();
        // ---- MFMA: 2 k-chunks of 32 ----
        #pragma unroll
        for (int kc = 0; kc < 2; ++kc) {
            int nrow = w * 16 + (l & 15);
            bfrag bf = w_lds[nrow * 8 + ((kc * 4 + (l >> 4)) ^ (nrow & 7))];
            #pragma unroll
            for (int rg = 0; rg < 4; ++rg) {
                int arow = rg * 16 + (l & 15);
                bfrag af = a_lds[arow * 8 + ((kc * 4 + (l >> 4)) ^ (arow & 7))];
                acc[rg] = __builtin_amdgcn_mfma_f32_16x16x32_bf16(af, bf, acc[rg], 0, 0, 0);
            }
        }
    }
    // ---- epilogue: D col = l&15, row = (l>>4)*4 + r ----
    #pragma unroll
    for (int rg = 0; rg < 4; ++rg) {
        #pragma unroll
        for (int r = 0; r < 4; ++r) {
            int row = rg * 16 + (l >> 4) * 4 + r;
            int col = n0 + w * 16 + (l & 15);
            part[((size_t)ks * 64 + row) * N + col] = acc[rg][r];
        }
    }
}

// ---------------------------------------------------------------------------
// Split-K reduce + per-head RMSNorm + RoPE.
// ---------------------------------------------------------------------------
__global__ __launch_bounds__(256) void rope_norm_kernel(
    const float* __restrict__ part1, const int* __restrict__ pos,
    const float* __restrict__ qn_w, const float* __restrict__ kn_w,
    float* __restrict__ qr, float* __restrict__ kr, float* __restrict__ vr)
{
    int row  = blockIdx.x * 4 + (threadIdx.x >> 6);
    int lane = threadIdx.x & 63;
    int b = row / 24, h = row % 24;
    int col, type;
    if (h < 16)      { type = 0; col = h * 128; }
    else if (h < 20) { type = 1; col = 2048 + (h - 16) * 128; }
    else             { type = 2; col = 2560 + (h - 20) * 128; }

    float t1 = 0.f, t2 = 0.f;
    #pragma unroll
    for (int ksp = 0; ksp < KSPLIT; ++ksp) {
        t1 += part1[((size_t)ksp * 64 + b) * 3072 + col + lane];
        t2 += part1[((size_t)ksp * 64 + b) * 3072 + col + lane + 64];
    }

    if (type == 2) {
        vr[(b * HK + (h - 20)) * 128 + lane]      = t1;
        vr[(b * HK + (h - 20)) * 128 + lane + 64] = t2;
        return;
    }

    float ss = t1 * t1 + t2 * t2;
    ss += __shfl_xor(ss, 1);  ss += __shfl_xor(ss, 2);  ss += __shfl_xor(ss, 4);
    ss += __shfl_xor(ss, 8);  ss += __shfl_xor(ss, 16); ss += __shfl_xor(ss, 32);
    float rn = 1.0f / sqrtf(ss * (1.0f / 128.0f) + EPS);
    const float* wn = (type == 0) ? qn_w : kn_w;
    float n1 = t1 * rn * wn[lane];
    float n2 = t2 * rn * wn[lane + 64];

    float invf = powf(10000.0f, -(float)lane * (1.0f / 64.0f));
    float f    = (float)pos[b] * invf;
    float sv = sinf(f), cv = cosf(f);
    float o1 = n1 * cv - n2 * sv;
    float o2 = n2 * cv + n1 * sv;

    if (type == 0) {
        qr[(b * HQ + h) * 128 + lane]      = o1;
        qr[(b * HQ + h) * 128 + lane + 64] = o2;
    } else {
        kr[(b * HK + (h - 16)) * 128 + lane]      = o1;
        kr[(b * HK + (h - 16)) * 128 + lane + 64] = o2;
    }
}

// ---------------------------------------------------------------------------
// Flash-decode attention (scale = 1.0) — round-11 structure (NSPLIT=4,
// 1024 blocks = 4/CU co-resident) + DEPTH-2 register prefetch.
// Each 32-lane half owns one position/iter; 128 iteration-indices per
// half-wave (positions wh + 8*i, i=0..127). Two named register sets (A,B)
// hold positions i and i+1; the loop computes a pair while loading the pair
// two indices ahead. Unguarded loads reach at most index 126 ->
// s = sp*1024 + wh + 1008 <= 4087 < 4095. Guarded final index 127
// (sp==3 && wh==7 -> s==4095 = appended token).
// ---------------------------------------------------------------------------
__global__ __launch_bounds__(256) void attn_kernel(
    const float* __restrict__ kc, const float* __restrict__ vc,
    const float* __restrict__ qr, const float* __restrict__ kr,
    const float* __restrict__ vr,
    float* __restrict__ pacc, float* __restrict__ pml)
{
    int blk  = blockIdx.x;
    int sp   = blk & (NSPLIT - 1);
    int hk   = (blk >> 2) & (HK - 1);
    int b    = blk >> 4;
    int t    = threadIdx.x;
    int wh   = t >> 5;            // 0..7: half-wave id within block
    int l32  = t & 31;
    int g    = t & 3;             // owned head within kv group
    int dbase = (l32 >> 2) * 16;  // owned d-chunk (16 floats)
    int sel1 = l32 & 1, sel2 = l32 & 2;

    float4 q4[G_];
    #pragma unroll
    for (int gg = 0; gg < G_; ++gg)
        q4[gg] = *(const float4*)&qr[(size_t)(b * HQ + hk * G_ + gg) * D_ + l32 * 4];

    const float* kbase = kc + (size_t)(b * HK + hk) * SPAST * D_;
    const float* vbase = vc + (size_t)(b * HK + hk) * SPAST * D_;
    const float* knew  = kr + (b * HK + hk) * D_;
    const float* vnew  = vr + (b * HK + hk) * D_;

    float  m = -1e30f, lsum = 0.f;
    float4 acc[4];
    #pragma unroll
    for (int j = 0; j < 4; ++j) acc[j] = make_float4(0.f, 0.f, 0.f, 0.f);

    auto COMPUTE = [&](const float4& k4, const float4* v4) {
        float p0 = q4[0].x*k4.x + q4[0].y*k4.y + q4[0].z*k4.z + q4[0].w*k4.w;
        float p1 = q4[1].x*k4.x + q4[1].y*k4.y + q4[1].z*k4.z + q4[1].w*k4.w;
        float p2 = q4[2].x*k4.x + q4[2].y*k4.y + q4[2].z*k4.z + q4[2].w*k4.w;
        float p3 = q4[3].x*k4.x + q4[3].y*k4.y + q4[3].z*k4.z + q4[3].w*k4.w;
        // transposed butterfly: lane ends with full score of head l32&3
        float ka = sel1 ? p1 : p0, sa = sel1 ? p0 : p1;
        float kb = sel1 ? p3 : p2, sb = sel1 ? p2 : p3;
        float s01 = ka + __shfl_xor(sa, 1);
        float s23 = kb + __shfl_xor(sb, 1);
        float kc2 = sel2 ? s23 : s01, sc = sel2 ? s01 : s23;
        float p = kc2 + __shfl_xor(sc, 2);
        p += __shfl_xor(p, 4);
        p += __shfl_xor(p, 8);
        p += __shfl_xor(p, 16);
        // defer-max online softmax (rescale rare)
        if (p > m + 8.0f) {
            float al = __expf(m - p);
            m = p;
            lsum *= al;
            #pragma unroll
            for (int j = 0; j < 4; ++j) {
                acc[j].x *= al; acc[j].y *= al; acc[j].z *= al; acc[j].w *= al;
            }
        }
        float e = __expf(p - m);
        lsum += e;
        #pragma unroll
        for (int j = 0; j < 4; ++j) {
            acc[j].x += e * v4[j].x; acc[j].y += e * v4[j].y;
            acc[j].z += e * v4[j].z; acc[j].w += e * v4[j].w;
        }
    };

    // set A holds even iteration-indices, set B odd; off/offB track them
    int off  = (sp * 1024 + wh) * D_;        // index 0
    int offB = off + 8 * D_;                 // index 1

    float4 kA = *(const float4*)(kbase + off + l32 * 4);
    float4 vA[4];
    #pragma unroll
    for (int j = 0; j < 4; ++j)
        vA[j] = *(const float4*)(vbase + off + dbase + j * 4);
    float4 kB = *(const float4*)(kbase + offB + l32 * 4);
    float4 vB[4];
    #pragma unroll
    for (int j = 0; j < 4; ++j)
        vB[j] = *(const float4*)(vbase + offB + dbase + j * 4);

    for (int ii = 0; ii < 62; ++ii) {
        // prefetch index 2ii+2 into temps, compute index 2ii (set A)
        int offn = off + 16 * D_;
        float4 kt = *(const float4*)(kbase + offn + l32 * 4);
        float4 vt0 = *(const float4*)(vbase + offn + dbase);
        float4 vt1 = *(const float4*)(vbase + offn + dbase + 4);
        float4 vt2 = *(const float4*)(vbase + offn + dbase + 8);
        float4 vt3 = *(const float4*)(vbase + offn + dbase + 12);
        COMPUTE(kA, vA);
        kA = kt; vA[0] = vt0; vA[1] = vt1; vA[2] = vt2; vA[3] = vt3;
        off = offn;
        // prefetch index 2ii+3 into temps, compute index 2ii+1 (set B)
        int offn2 = offB + 16 * D_;
        float4 ku = *(const float4*)(kbase + offn2 + l32 * 4);
        float4 vu0 = *(const float4*)(vbase + offn2 + dbase);
        float4 vu1 = *(const float4*)(vbase + offn2 + dbase + 4);
        float4 vu2 = *(const float4*)(vbase + offn2 + dbase + 8);
        float4 vu3 = *(const float4*)(vbase + offn2 + dbase + 12);
        COMPUTE(kB, vB);
        kB = ku; vB[0] = vu0; vB[1] = vu1; vB[2] = vu2; vB[3] = vu3;
        offB = offn2;
    }
    // after loop: A = index 124, B = index 125
    {
        // prefetch index 126 (max s = 4087 < SPAST), compute 124
        int offn = off + 16 * D_;
        float4 kt = *(const float4*)(kbase + offn + l32 * 4);
        float4 vt0 = *(const float4*)(vbase + offn + dbase);
        float4 vt1 = *(const float4*)(vbase + offn + dbase + 4);
        float4 vt2 = *(const float4*)(vbase + offn + dbase + 8);
        float4 vt3 = *(const float4*)(vbase + offn + dbase + 12);
        COMPUTE(kA, vA);
        kA = kt; vA[0] = vt0; vA[1] = vt1; vA[2] = vt2; vA[3] = vt3;
    }
    COMPUTE(kB, vB);   // index 125
    COMPUTE(kA, vA);   // index 126
    {   // guarded final index 127; only sp==3, wh==7 hits the new token
        int s_f = sp * 1024 + 1016 + wh;
        const float* kp = (s_f < SPAST) ? (kbase + (size_t)s_f * D_ + l32 * 4)
                                        : (knew + l32 * 4);
        const float* vp = (s_f < SPAST) ? (vbase + (size_t)s_f * D_ + dbase)
                                        : (vnew + dbase);
        kA = *(const float4*)kp;
        #pragma unroll
        for (int j = 0; j < 4; ++j) vA[j] = *(const float4*)(vp + j * 4);
        COMPUTE(kA, vA);
    }

    // merge 8 half-wave partials within the block via LDS
    __shared__ float s_acc[8][G_][D_];
    __shared__ float s_m[8][G_];
    __shared__ float s_l[8][G_];
    #pragma unroll
    for (int j = 0; j < 4; ++j)
        *(float4*)&s_acc[wh][g][dbase + j * 4] = acc[j];
    if (l32 < 4) { s_m[wh][l32] = m; s_l[wh][l32] = lsum; }
    __syncthreads();

    if (t < 128) {
        int d = t;
        #pragma unroll
        for (int gg = 0; gg < G_; ++gg) {
            float M = -1e30f;
            #pragma unroll
            for (int j = 0; j < 8; ++j) M = fmaxf(M, s_m[j][gg]);
            float L = 0.f, a = 0.f;
            #pragma unroll
            for (int j = 0; j < 8; ++j) {
                float e = __expf(s_m[j][gg] - M);
                L += e * s_l[j][gg];
                a += e * s_acc[j][gg][d];
            }
            int hq = hk * G_ + gg;
            size_t pidx = (size_t)(b * HQ + hq) * NSPLIT + sp;
            pacc[pidx * D_ + d] = a;
            if (d == 0) { pml[pidx * 2 + 0] = M; pml[pidx * 2 + 1] = L; }
        }
    }
}

// ---------------------------------------------------------------------------
// Merge NSPLIT partials; write attn row as bf16 for the O-projection.
// ---------------------------------------------------------------------------
__global__ void attn_combine_kernel(const float* __restrict__ pacc,
                                    const float* __restrict__ pml,
                                    ushort_t* __restrict__ attnb)
{
    int bh = blockIdx.x;
    int d  = threadIdx.x;
    float M = -1e30f;
    #pragma unroll
    for (int s = 0; s < NSPLIT; ++s)
        M = fmaxf(M, pml[(size_t)(bh * NSPLIT + s) * 2]);
    float L = 0.f, a = 0.f;
    #pragma unroll
    for (int s = 0; s < NSPLIT; ++s) {
        float e = __expf(pml[(size_t)(bh * NSPLIT + s) * 2] - M);
        L += e * pml[(size_t)(bh * NSPLIT + s) * 2 + 1];
        a += e * pacc[(size_t)(bh * NSPLIT + s) * D_ + d];
    }
    attnb[(size_t)bh * D_ + d] = f2bf(a / L);
}

// ---------------------------------------------------------------------------
__global__ void sum_parts_kernel(const float* __restrict__ part,
                                 float* __restrict__ out)
{
    int i = blockIdx.x * 256 + threadIdx.x;
    float v = 0.f;
    #pragma unroll
    for (int ksp = 0; ksp < KSPLIT; ++ksp)
        v += part[(size_t)ksp * B_ * DIM + i];
    out[i] = v;
}

// ---------------------------------------------------------------------------
extern "C" void kernel_launch(void* const* d_in, const int* in_sizes, int n_in,
                              void* d_out, int out_size, void* d_ws, size_t ws_size,
                              hipStream_t stream)
{
    const float* x   = (const float*)d_in[0];
    const int*   pos = (const int*)  d_in[1];
    const float* kc  = (const float*)d_in[2];
    const float* vc  = (const float*)d_in[3];
    const float* Wq  = (const float*)d_in[4];
    const float* Wk  = (const float*)d_in[5];
    const float* Wv  = (const float*)d_in[6];
    const float* Wo  = (const float*)d_in[7];
    const float* qn  = (const float*)d_in[8];
    const float* kn  = (const float*)d_in[9];

    float* ws    = (float*)d_ws;
    float* part1 = ws;                                       // KSPLIT*64*3072
    float* qr    = part1 + (size_t)KSPLIT * 64 * 3072;
    float* kr    = qr    + (size_t)64 * HQ * D_;
    float* vr    = kr    + (size_t)64 * HK * D_;
    float* pacc  = vr    + (size_t)64 * HK * D_;
    float* pml   = pacc  + (size_t)64 * HQ * NSPLIT * D_;
    float* attnb = pml   + (size_t)64 * HQ * NSPLIT * 2;     // used as ushort
    float* part4 = attnb + (size_t)64 * DIM;                 // KSPLIT*64*2048

    gemm_mfma_kernel<false><<<dim3(48, KSPLIT), 256, 0, stream>>>(
        x, Wq, Wk, Wv, part1, 3072);
    rope_norm_kernel<<<384, 256, 0, stream>>>(part1, pos, qn, kn, qr, kr, vr);
    attn_kernel<<<B_ * HK * NSPLIT, 256, 0, stream>>>(kc, vc, qr, kr, vr, pacc, pml);
    attn_combine_kernel<<<B_ * HQ, 128, 0, stream>>>(pacc, pml, (ushort_t*)attnb);
    gemm_mfma_kernel<true><<<dim3(32, KSPLIT), 256, 0, stream>>>(
        attnb, Wo, Wo, Wo, part4, 2048);
    sum_parts_kernel<<<(B_ * DIM) / 256, 256, 0, stream>>>(part4, (float*)d_out);
}

// Round 13
// 217.514 us; speedup vs baseline: 1.0876x; 1.0876x over previous
//
#include <hip/hip_runtime.h>
#include <math.h>

#define DIM    2048
#define B_     64
#define HQ     16
#define HK     4
#define G_     4
#define D_     128
#define SPAST  4095
#define SEQ    4096
#define NSPLIT 4
#define KSPLIT 8
#define EPS    1e-5f

typedef short bfrag __attribute__((ext_vector_type(8)));   // 8 bf16 (4 VGPR)
typedef float facc  __attribute__((ext_vector_type(4)));   // 4 f32 acc
typedef unsigned short ushort_t;

// fp32 -> bf16, round-to-nearest-even
__device__ inline unsigned short f2bf(float f) {
    unsigned u = __float_as_uint(f);
    return (unsigned short)((u + 0x7FFFu + ((u >> 16) & 1u)) >> 16);
}

// ---------------------------------------------------------------------------
// bf16-MFMA split-K GEMM (round-8 version, measured best).
// ---------------------------------------------------------------------------
template<bool ABF16>
__global__ __launch_bounds__(256) void gemm_mfma_kernel(
    const void* __restrict__ Aptr,
    const float* __restrict__ W0, const float* __restrict__ W1,
    const float* __restrict__ W2,
    float* __restrict__ part, int N)
{
    const int K  = 2048;
    const int KS = K / KSPLIT;   // 256
    int n0 = blockIdx.x * 64;
    int ks = blockIdx.y;
    const float* W; int wc;
    if (n0 < 2048)      { W = W0; wc = n0; }
    else if (n0 < 2560) { W = W1; wc = n0 - 2048; }
    else                { W = W2; wc = n0 - 2560; }

    __shared__ bfrag a_lds[64 * 8];   // [row][chunk] 8 chunks of 8 bf16
    __shared__ bfrag w_lds[64 * 8];

    int t = threadIdx.x;
    int w = t >> 6, l = t & 63;
    int row_s = t >> 2;          // staging row 0..63 (4 threads per row)
    int q_s   = t & 3;           // staging quad: 16 elements at q_s*16
    int sw_s  = row_s & 7;
    int c0    = q_s * 2;

    facc acc[4] = {};

    const float*    Af = (const float*)Aptr;
    const ushort_t* Ab = (const ushort_t*)Aptr;
    size_t a_off = (size_t)row_s * K + (size_t)ks * KS + q_s * 16;
    const float* Wbase = W + (size_t)(wc + row_s) * K + (size_t)ks * KS + q_s * 16;

    for (int kt = 0; kt < KS; kt += 64) {
        __syncthreads();
        // ---- stage A tile ----
        if constexpr (ABF16) {
            const ushort_t* p = Ab + a_off + kt;
            bfrag v0 = *(const bfrag*)(p);
            bfrag v1 = *(const bfrag*)(p + 8);
            a_lds[row_s * 8 + ((c0    ) ^ sw_s)] = v0;
            a_lds[row_s * 8 + ((c0 + 1) ^ sw_s)] = v1;
        } else {
            const float* p = Af + a_off + kt;
            float4 f0 = *(const float4*)(p);
            float4 f1 = *(const float4*)(p + 4);
            float4 f2 = *(const float4*)(p + 8);
            float4 f3 = *(const float4*)(p + 12);
            bfrag v0, v1;
            v0[0]=f2bf(f0.x); v0[1]=f2bf(f0.y); v0[2]=f2bf(f0.z); v0[3]=f2bf(f0.w);
            v0[4]=f2bf(f1.x); v0[5]=f2bf(f1.y); v0[6]=f2bf(f1.z); v0[7]=f2bf(f1.w);
            v1[0]=f2bf(f2.x); v1[1]=f2bf(f2.y); v1[2]=f2bf(f2.z); v1[3]=f2bf(f2.w);
            v1[4]=f2bf(f3.x); v1[5]=f2bf(f3.y); v1[6]=f2bf(f3.z); v1[7]=f2bf(f3.w);
            a_lds[row_s * 8 + ((c0    ) ^ sw_s)] = v0;
            a_lds[row_s * 8 + ((c0 + 1) ^ sw_s)] = v1;
        }
        // ---- stage W tile (fp32 -> bf16) ----
        {
            const float* p = Wbase + kt;
            float4 f0 = *(const float4*)(p);
            float4 f1 = *(const float4*)(p + 4);
            float4 f2 = *(const float4*)(p + 8);
            float4 f3 = *(const float4*)(p + 12);
            bfrag v0, v1;
            v0[0]=f2bf(f0.x); v0[1]=f2bf(f0.y); v0[2]=f2bf(f0.z); v0[3]=f2bf(f0.w);
            v0[4]=f2bf(f1.x); v0[5]=f2bf(f1.y); v0[6]=f2bf(f1.z); v0[7]=f2bf(f1.w);
            v1[0]=f2bf(f2.x); v1[1]=f2bf(f2.y); v1[2]=f2bf(f2.z); v1[3]=f2bf(f2.w);
            v1[4]=f2bf(f3.x); v1[5]=f2bf(f3.y); v1[6]=f2bf(f3.z); v1[7]=f2bf(f3.w);
            w_lds[row_s * 8 + ((c0    ) ^ sw_s)] = v0;
            w_lds[row_s * 8 + ((c0 + 1) ^ sw_s)] = v1;
        }
        __syncthreads();
        // ---- MFMA: 2 k-chunks of 32 ----
        #pragma unroll
        for (int kc = 0; kc < 2; ++kc) {
            int nrow = w * 16 + (l & 15);
            bfrag bf = w_lds[nrow * 8 + ((kc * 4 + (l >> 4)) ^ (nrow & 7))];
            #pragma unroll
            for (int rg = 0; rg < 4; ++rg) {
                int arow = rg * 16 + (l & 15);
                bfrag af = a_lds[arow * 8 + ((kc * 4 + (l >> 4)) ^ (arow & 7))];
                acc[rg] = __builtin_amdgcn_mfma_f32_16x16x32_bf16(af, bf, acc[rg], 0, 0, 0);
            }
        }
    }
    // ---- epilogue: D col = l&15, row = (l>>4)*4 + r ----
    #pragma unroll
    for (int rg = 0; rg < 4; ++rg) {
        #pragma unroll
        for (int r = 0; r < 4; ++r) {
            int row = rg * 16 + (l >> 4) * 4 + r;
            int col = n0 + w * 16 + (l & 15);
            part[((size_t)ks * 64 + row) * N + col] = acc[rg][r];
        }
    }
}

// ---------------------------------------------------------------------------
// Split-K reduce + per-head RMSNorm + RoPE.
// ---------------------------------------------------------------------------
__global__ __launch_bounds__(256) void rope_norm_kernel(
    const float* __restrict__ part1, const int* __restrict__ pos,
    const float* __restrict__ qn_w, const float* __restrict__ kn_w,
    float* __restrict__ qr, float* __restrict__ kr, float* __restrict__ vr)
{
    int row  = blockIdx.x * 4 + (threadIdx.x >> 6);
    int lane = threadIdx.x & 63;
    int b = row / 24, h = row % 24;
    int col, type;
    if (h < 16)      { type = 0; col = h * 128; }
    else if (h < 20) { type = 1; col = 2048 + (h - 16) * 128; }
    else             { type = 2; col = 2560 + (h - 20) * 128; }

    float t1 = 0.f, t2 = 0.f;
    #pragma unroll
    for (int ksp = 0; ksp < KSPLIT; ++ksp) {
        t1 += part1[((size_t)ksp * 64 + b) * 3072 + col + lane];
        t2 += part1[((size_t)ksp * 64 + b) * 3072 + col + lane + 64];
    }

    if (type == 2) {
        vr[(b * HK + (h - 20)) * 128 + lane]      = t1;
        vr[(b * HK + (h - 20)) * 128 + lane + 64] = t2;
        return;
    }

    float ss = t1 * t1 + t2 * t2;
    ss += __shfl_xor(ss, 1);  ss += __shfl_xor(ss, 2);  ss += __shfl_xor(ss, 4);
    ss += __shfl_xor(ss, 8);  ss += __shfl_xor(ss, 16); ss += __shfl_xor(ss, 32);
    float rn = 1.0f / sqrtf(ss * (1.0f / 128.0f) + EPS);
    const float* wn = (type == 0) ? qn_w : kn_w;
    float n1 = t1 * rn * wn[lane];
    float n2 = t2 * rn * wn[lane + 64];

    float invf = powf(10000.0f, -(float)lane * (1.0f / 64.0f));
    float f    = (float)pos[b] * invf;
    float sv = sinf(f), cv = cosf(f);
    float o1 = n1 * cv - n2 * sv;
    float o2 = n2 * cv + n1 * sv;

    if (type == 0) {
        qr[(b * HQ + h) * 128 + lane]      = o1;
        qr[(b * HQ + h) * 128 + lane + 64] = o2;
    } else {
        kr[(b * HK + (h - 16)) * 128 + lane]      = o1;
        kr[(b * HK + (h - 16)) * 128 + lane + 64] = o2;
    }
}

// ---------------------------------------------------------------------------
// Flash-decode attention (scale = 1.0) — round-11 champion (measured 217.6).
// Grid: B*HK*NSPLIT = 1024 blocks (exactly 4/CU -> all co-resident, no
// scheduling tail), 4 waves. Each 32-lane half owns one position/iter
// (8 positions/block/iter, 128 iters over 1024 positions). K and V both
// prefetched one position ahead; 126 unguarded iterations, one drain, one
// guarded final iteration (sp==3 && wh==7 -> s==4095). In-loop prefetch
// reaches at most sp*1024 + wh + 1008 <= 4087 < 4095.
// ---------------------------------------------------------------------------
__global__ __launch_bounds__(256) void attn_kernel(
    const float* __restrict__ kc, const float* __restrict__ vc,
    const float* __restrict__ qr, const float* __restrict__ kr,
    const float* __restrict__ vr,
    float* __restrict__ pacc, float* __restrict__ pml)
{
    int blk  = blockIdx.x;
    int sp   = blk & (NSPLIT - 1);
    int hk   = (blk >> 2) & (HK - 1);
    int b    = blk >> 4;
    int t    = threadIdx.x;
    int wh   = t >> 5;            // 0..7: half-wave id within block
    int l32  = t & 31;
    int g    = t & 3;             // owned head within kv group
    int dbase = (l32 >> 2) * 16;  // owned d-chunk (16 floats)
    int sel1 = l32 & 1, sel2 = l32 & 2;

    float4 q4[G_];
    #pragma unroll
    for (int gg = 0; gg < G_; ++gg)
        q4[gg] = *(const float4*)&qr[(size_t)(b * HQ + hk * G_ + gg) * D_ + l32 * 4];

    const float* kbase = kc + (size_t)(b * HK + hk) * SPAST * D_;
    const float* vbase = vc + (size_t)(b * HK + hk) * SPAST * D_;
    const float* knew  = kr + (b * HK + hk) * D_;
    const float* vnew  = vr + (b * HK + hk) * D_;

    float  m = -1e30f, lsum = 0.f;
    float4 acc[4];
    #pragma unroll
    for (int j = 0; j < 4; ++j) acc[j] = make_float4(0.f, 0.f, 0.f, 0.f);

    auto COMPUTE = [&](const float4& k4, const float4* v4) {
        float p0 = q4[0].x*k4.x + q4[0].y*k4.y + q4[0].z*k4.z + q4[0].w*k4.w;
        float p1 = q4[1].x*k4.x + q4[1].y*k4.y + q4[1].z*k4.z + q4[1].w*k4.w;
        float p2 = q4[2].x*k4.x + q4[2].y*k4.y + q4[2].z*k4.z + q4[2].w*k4.w;
        float p3 = q4[3].x*k4.x + q4[3].y*k4.y + q4[3].z*k4.z + q4[3].w*k4.w;
        // transposed butterfly: lane ends with full score of head l32&3
        float ka = sel1 ? p1 : p0, sa = sel1 ? p0 : p1;
        float kb = sel1 ? p3 : p2, sb = sel1 ? p2 : p3;
        float s01 = ka + __shfl_xor(sa, 1);
        float s23 = kb + __shfl_xor(sb, 1);
        float kc2 = sel2 ? s23 : s01, sc = sel2 ? s01 : s23;
        float p = kc2 + __shfl_xor(sc, 2);
        p += __shfl_xor(p, 4);
        p += __shfl_xor(p, 8);
        p += __shfl_xor(p, 16);
        // defer-max online softmax (rescale rare)
        if (p > m + 8.0f) {
            float al = __expf(m - p);
            m = p;
            lsum *= al;
            #pragma unroll
            for (int j = 0; j < 4; ++j) {
                acc[j].x *= al; acc[j].y *= al; acc[j].z *= al; acc[j].w *= al;
            }
        }
        float e = __expf(p - m);
        lsum += e;
        #pragma unroll
        for (int j = 0; j < 4; ++j) {
            acc[j].x += e * v4[j].x; acc[j].y += e * v4[j].y;
            acc[j].z += e * v4[j].z; acc[j].w += e * v4[j].w;
        }
    };

    int off = (sp * 1024 + wh) * D_;  // element offset of first owned position
    float4 k4 = *(const float4*)(kbase + off + l32 * 4);
    float4 v4[4];
    #pragma unroll
    for (int j = 0; j < 4; ++j)
        v4[j] = *(const float4*)(vbase + off + dbase + j * 4);

    for (int i = 0; i < 126; ++i) {
        int offn = off + 8 * D_;
        float4 k4n = *(const float4*)(kbase + offn + l32 * 4);
        float4 v4n[4];
        #pragma unroll
        for (int j = 0; j < 4; ++j)
            v4n[j] = *(const float4*)(vbase + offn + dbase + j * 4);
        COMPUTE(k4, v4);
        k4 = k4n;
        #pragma unroll
        for (int j = 0; j < 4; ++j) v4[j] = v4n[j];
        off = offn;
    }
    COMPUTE(k4, v4);   // drain: position sp*1024 + wh + 1008
    {   // guarded final position; only sp==3, wh==7 hits the new token
        int s_f = sp * 1024 + 1016 + wh;
        const float* kp = (s_f < SPAST) ? (kbase + (size_t)s_f * D_ + l32 * 4)
                                        : (knew + l32 * 4);
        const float* vp = (s_f < SPAST) ? (vbase + (size_t)s_f * D_ + dbase)
                                        : (vnew + dbase);
        k4 = *(const float4*)kp;
        #pragma unroll
        for (int j = 0; j < 4; ++j) v4[j] = *(const float4*)(vp + j * 4);
        COMPUTE(k4, v4);
    }

    // merge 8 half-wave partials within the block via LDS
    __shared__ float s_acc[8][G_][D_];
    __shared__ float s_m[8][G_];
    __shared__ float s_l[8][G_];
    #pragma unroll
    for (int j = 0; j < 4; ++j)
        *(float4*)&s_acc[wh][g][dbase + j * 4] = acc[j];
    if (l32 < 4) { s_m[wh][l32] = m; s_l[wh][l32] = lsum; }
    __syncthreads();

    if (t < 128) {
        int d = t;
        #pragma unroll
        for (int gg = 0; gg < G_; ++gg) {
            float M = -1e30f;
            #pragma unroll
            for (int j = 0; j < 8; ++j) M = fmaxf(M, s_m[j][gg]);
            float L = 0.f, a = 0.f;
            #pragma unroll
            for (int j = 0; j < 8; ++j) {
                float e = __expf(s_m[j][gg] - M);
                L += e * s_l[j][gg];
                a += e * s_acc[j][gg][d];
            }
            int hq = hk * G_ + gg;
            size_t pidx = (size_t)(b * HQ + hq) * NSPLIT + sp;
            pacc[pidx * D_ + d] = a;
            if (d == 0) { pml[pidx * 2 + 0] = M; pml[pidx * 2 + 1] = L; }
        }
    }
}

// ---------------------------------------------------------------------------
// Merge NSPLIT partials; write attn row as bf16 for the O-projection.
// ---------------------------------------------------------------------------
__global__ void attn_combine_kernel(const float* __restrict__ pacc,
                                    const float* __restrict__ pml,
                                    ushort_t* __restrict__ attnb)
{
    int bh = blockIdx.x;
    int d  = threadIdx.x;
    float M = -1e30f;
    #pragma unroll
    for (int s = 0; s < NSPLIT; ++s)
        M = fmaxf(M, pml[(size_t)(bh * NSPLIT + s) * 2]);
    float L = 0.f, a = 0.f;
    #pragma unroll
    for (int s = 0; s < NSPLIT; ++s) {
        float e = __expf(pml[(size_t)(bh * NSPLIT + s) * 2] - M);
        L += e * pml[(size_t)(bh * NSPLIT + s) * 2 + 1];
        a += e * pacc[(size_t)(bh * NSPLIT + s) * D_ + d];
    }
    attnb[(size_t)bh * D_ + d] = f2bf(a / L);
}

// ---------------------------------------------------------------------------
__global__ void sum_parts_kernel(const float* __restrict__ part,
                                 float* __restrict__ out)
{
    int i = blockIdx.x * 256 + threadIdx.x;
    float v = 0.f;
    #pragma unroll
    for (int ksp = 0; ksp < KSPLIT; ++ksp)
        v += part[(size_t)ksp * B_ * DIM + i];
    out[i] = v;
}

// ---------------------------------------------------------------------------
extern "C" void kernel_launch(void* const* d_in, const int* in_sizes, int n_in,
                              void* d_out, int out_size, void* d_ws, size_t ws_size,
                              hipStream_t stream)
{
    const float* x   = (const float*)d_in[0];
    const int*   pos = (const int*)  d_in[1];
    const float* kc  = (const float*)d_in[2];
    const float* vc  = (const float*)d_in[3];
    const float* Wq  = (const float*)d_in[4];
    const float* Wk  = (const float*)d_in[5];
    const float* Wv  = (const float*)d_in[6];
    const float* Wo  = (const float*)d_in[7];
    const float* qn  = (const float*)d_in[8];
    const float* kn  = (const float*)d_in[9];

    float* ws    = (float*)d_ws;
    float* part1 = ws;                                       // KSPLIT*64*3072
    float* qr    = part1 + (size_t)KSPLIT * 64 * 3072;
    float* kr    = qr    + (size_t)64 * HQ * D_;
    float* vr    = kr    + (size_t)64 * HK * D_;
    float* pacc  = vr    + (size_t)64 * HK * D_;
    float* pml   = pacc  + (size_t)64 * HQ * NSPLIT * D_;
    float* attnb = pml   + (size_t)64 * HQ * NSPLIT * 2;     // used as ushort
    float* part4 = attnb + (size_t)64 * DIM;                 // KSPLIT*64*2048

    gemm_mfma_kernel<false><<<dim3(48, KSPLIT), 256, 0, stream>>>(
        x, Wq, Wk, Wv, part1, 3072);
    rope_norm_kernel<<<384, 256, 0, stream>>>(part1, pos, qn, kn, qr, kr, vr);
    attn_kernel<<<B_ * HK * NSPLIT, 256, 0, stream>>>(kc, vc, qr, kr, vr, pacc, pml);
    attn_combine_kernel<<<B_ * HQ, 128, 0, stream>>>(pacc, pml, (ushort_t*)attnb);
    gemm_mfma_kernel<true><<<dim3(32, KSPLIT), 256, 0, stream>>>(
        attnb, Wo, Wo, Wo, part4, 2048);
    sum_parts_kernel<<<(B_ * DIM) / 256, 256, 0, stream>>>(part4, (float*)d_out);
}